// Round 2
// baseline (719.159 us; speedup 1.0000x reference)
//
#include <hip/hip_runtime.h>

#define NROWS 65536
#define ADIM  1024
#define CCLS  1000
#define SAUG  2
#define MROWS (NROWS + SAUG*CCLS)   /* 67536 */
#define MPAD  67584                 /* 264*256 */
#define NPAD  1024
#define NPART 4                     /* 4 col-splits; wave-col partials merged in LDS */
#define NEG_INF (-3.0e38f)

typedef __bf16 bf16x8 __attribute__((ext_vector_type(8)));
typedef float  f32x4  __attribute__((ext_vector_type(4)));
typedef unsigned short u16;

__device__ __forceinline__ unsigned pk2bf(float a, float b){
  unsigned ua = __float_as_uint(a), ub = __float_as_uint(b);
  ua = (ua + 0x7FFFu + ((ua>>16)&1u)) >> 16;
  ub = (ub + 0x7FFFu + ((ub>>16)&1u)) >> 16;
  return ua | (ub<<16);
}
__device__ __forceinline__ float bflo(unsigned u){ return __uint_as_float((u & 0xFFFFu) << 16); }
__device__ __forceinline__ float bfhi(unsigned u){ return __uint_as_float(u & 0xFFFF0000u); }

// ---------------- histogram of labels ----------------
__global__ void k_hist(const int* __restrict__ tgt, int* __restrict__ cnt){
  int i = blockIdx.x*blockDim.x + threadIdx.x;
  int stride = gridDim.x*blockDim.x;
  for (; i < NROWS; i += stride) atomicAdd(&cnt[tgt[i]], 1);
}

// ---------------- exclusive scan over 1000 counts ----------------
__global__ void k_scan(const int* __restrict__ cnt, int* __restrict__ start){
  __shared__ int s[1024];
  int t = threadIdx.x;
  int v = (t < CCLS) ? cnt[t] : 0;
  s[t] = v;
  __syncthreads();
  for (int off = 1; off < 1024; off <<= 1){
    int u = (t >= off) ? s[t-off] : 0;
    __syncthreads();
    s[t] += u;
    __syncthreads();
  }
  if (t < CCLS) start[t] = s[t] - v;   // exclusive
}

// ---------------- scatter row indices grouped by class ----------------
__global__ void k_scatter(const int* __restrict__ tgt, const int* __restrict__ start,
                          int* __restrict__ pos, int* __restrict__ sorted){
  int i = blockIdx.x*blockDim.x + threadIdx.x;
  int stride = gridDim.x*blockDim.x;
  for (; i < NROWS; i += stride){
    int c = tgt[i];
    int r = atomicAdd(&pos[c], 1);
    sorted[start[c] + r] = i;
  }
}

// ---------------- x rows -> bf16 ----------------
__global__ void k_cvt_x(const float* __restrict__ x, u16* __restrict__ xb){
  size_t i = ((size_t)blockIdx.x*blockDim.x + threadIdx.x)*8;
  float4 a = *(const float4*)(x+i);
  float4 b = *(const float4*)(x+i+4);
  uint4 o;
  o.x = pk2bf(a.x,a.y); o.y = pk2bf(a.z,a.w);
  o.z = pk2bf(b.x,b.y); o.w = pk2bf(b.z,b.w);
  *(uint4*)(xb+i) = o;
}

// ---------------- zero pad tail rows of xb ----------------
__global__ void k_pad(u16* __restrict__ xb){
  size_t i = ((size_t)blockIdx.x*blockDim.x + threadIdx.x)*8 + (size_t)MROWS*ADIM;
  uint4 z = {0u,0u,0u,0u};
  *(uint4*)(xb+i) = z;
}

// ---------------- fc_w -> bf16 (pad classes to 1024 with zeros) ----------------
__global__ void k_cvt_w(const float* __restrict__ w, u16* __restrict__ wb){
  size_t i = ((size_t)blockIdx.x*blockDim.x + threadIdx.x)*8;
  int row = (int)(i >> 10);
  uint4 o = {0u,0u,0u,0u};
  if (row < CCLS){
    float4 a = *(const float4*)(w+i);
    float4 b = *(const float4*)(w+i+4);
    o.x = pk2bf(a.x,a.y); o.y = pk2bf(a.z,a.w);
    o.z = pk2bf(b.x,b.y); o.w = pk2bf(b.z,b.w);
  }
  *(uint4*)(wb+i) = o;
}

// ---------------- combined bias (NEG_INF masks pad classes) ----------------
__global__ void k_bias(const float* __restrict__ fc_b, const float* __restrict__ ba,
                       float* __restrict__ biasv){
  int c = blockIdx.x*blockDim.x + threadIdx.x;
  if (c < NPAD) biasv[c] = (c < CCLS) ? fc_b[c] - ba[c] : NEG_INF;
}

// ---------------- per-class stats + augmentation rows ----------------
// Indices staged to LDS; 4-way unrolled gathers for memory-level parallelism.
__global__ void k_stats(const u16* __restrict__ xb_in, const int* __restrict__ sorted,
                        const int* __restrict__ cnt, const int* __restrict__ start,
                        const float* __restrict__ amt_p, const float* __restrict__ cov_p,
                        const float* __restrict__ ave_p, const float* __restrict__ eps,
                        u16* __restrict__ xb){
  __shared__ int sidx[256];
  int c = blockIdx.x;
  int t = threadIdx.x;
  int col = t*4;
  int n = cnt[c];
  int st = start[c];
  float s[4] = {0.f,0.f,0.f,0.f}, q[4] = {0.f,0.f,0.f,0.f};
  for (int base = 0; base < n; base += 256){
    int m = min(256, n - base);
    __syncthreads();
    if (t < m) sidx[t] = sorted[st + base + t];
    __syncthreads();
    int i = 0;
    for (; i + 4 <= m; i += 4){
      int r0 = sidx[i], r1 = sidx[i+1], r2 = sidx[i+2], r3 = sidx[i+3];
      uint2 u0 = *(const uint2*)(xb_in + (size_t)r0*ADIM + col);
      uint2 u1 = *(const uint2*)(xb_in + (size_t)r1*ADIM + col);
      uint2 u2 = *(const uint2*)(xb_in + (size_t)r2*ADIM + col);
      uint2 u3 = *(const uint2*)(xb_in + (size_t)r3*ADIM + col);
      {
        float v0=bflo(u0.x), v1=bfhi(u0.x), v2=bflo(u0.y), v3=bfhi(u0.y);
        s[0]+=v0; s[1]+=v1; s[2]+=v2; s[3]+=v3;
        q[0]+=v0*v0; q[1]+=v1*v1; q[2]+=v2*v2; q[3]+=v3*v3;
      }
      {
        float v0=bflo(u1.x), v1=bfhi(u1.x), v2=bflo(u1.y), v3=bfhi(u1.y);
        s[0]+=v0; s[1]+=v1; s[2]+=v2; s[3]+=v3;
        q[0]+=v0*v0; q[1]+=v1*v1; q[2]+=v2*v2; q[3]+=v3*v3;
      }
      {
        float v0=bflo(u2.x), v1=bfhi(u2.x), v2=bflo(u2.y), v3=bfhi(u2.y);
        s[0]+=v0; s[1]+=v1; s[2]+=v2; s[3]+=v3;
        q[0]+=v0*v0; q[1]+=v1*v1; q[2]+=v2*v2; q[3]+=v3*v3;
      }
      {
        float v0=bflo(u3.x), v1=bfhi(u3.x), v2=bflo(u3.y), v3=bfhi(u3.y);
        s[0]+=v0; s[1]+=v1; s[2]+=v2; s[3]+=v3;
        q[0]+=v0*v0; q[1]+=v1*v1; q[2]+=v2*v2; q[3]+=v3*v3;
      }
    }
    for (; i < m; i++){
      int row = sidx[i];
      const uint2 uv = *(const uint2*)(xb_in + (size_t)row*ADIM + col);
      float v0 = bflo(uv.x), v1 = bfhi(uv.x), v2 = bflo(uv.y), v3 = bfhi(uv.y);
      s[0]+=v0; s[1]+=v1; s[2]+=v2; s[3]+=v3;
      q[0]+=v0*v0; q[1]+=v1*v1; q[2]+=v2*v2; q[3]+=v3*v3;
    }
  }
  float cf = (float)n;
  float cc = (n == 0) ? 1.f : cf;
  float wgt = cf / (cf + amt_p[c] + 1e-10f);
  float4 cv = *(const float4*)(cov_p + (size_t)c*ADIM + col);
  float4 av = *(const float4*)(ave_p + (size_t)c*ADIM + col);
  float cvp[4] = {cv.x,cv.y,cv.z,cv.w};
  float avp[4] = {av.x,av.y,av.z,av.w};
  float ncov[4], nave[4];
  #pragma unroll
  for (int j = 0; j < 4; j++){
    float ave = s[j]/cc;
    float var = (q[j] - 2.f*ave*s[j] + cf*ave*ave)/cc;
    if (var <= 0.f) var = 1e-10f;
    float add = wgt*(1.f-wgt)*(avp[j]-ave)*(avp[j]-ave);
    ncov[j] = cvp[j]*(1.f-wgt) + var*wgt + add;
    nave[j] = avp[j]*(1.f-wgt) + ave*wgt;
  }
  #pragma unroll
  for (int s_ = 0; s_ < SAUG; s_++){
    size_t eoff = ((size_t)(s_*CCLS + c))*ADIM + col;
    size_t roff = ((size_t)(NROWS + s_*CCLS + c))*ADIM + col;
    const float4 e = *(const float4*)(eps + eoff);
    uint2 o;
    o.x = pk2bf(nave[0]+ncov[0]*e.x, nave[1]+ncov[1]*e.y);
    o.y = pk2bf(nave[2]+ncov[2]*e.z, nave[3]+ncov[3]*e.w);
    *(uint2*)(xb + roff) = o;
  }
}

// ---------------- MFMA GEMM + softmax partials ----------------
// tile 256x256, BK=32, 8 waves (2M x 4N), wave tile 128x64
// 4-deep LDS ring; cross-tile REGISTER double-buffering:
//   iter kt: barrier; STG(kt+3); vmcnt(4); ds_read tile kt+1 -> other frag set;
//            lgkmcnt(12) [in-order DS => tile-kt frags done]; 32 MFMA on tile kt.
// Swizzle off^=((off>>7)&3)<<4 on gload SOURCE + ds_read addr (both-sides, rule 21).
__global__ __launch_bounds__(512,2) void k_gemm_part(
    const u16* __restrict__ xb, const u16* __restrict__ wb,
    const float* __restrict__ biasv, const int* __restrict__ tgt,
    float* __restrict__ pm, float* __restrict__ pl, float* __restrict__ plab){
  extern __shared__ char smem[];
  const int t = threadIdx.x;
  const int lane = t & 63;
  const int wv = t >> 6;       // 0..7
  const int wr = wv >> 2;      // M half (128 rows)
  const int wc = wv & 3;       // N quarter (64 cols)
  const int col = lane & 15;
  const int quad = lane >> 4;

  // bijective XCD-chunk swizzle: 1056 blocks, 8 XCDs, 132 per chunk
  const int bid = blockIdx.x;
  const int wg  = (bid & 7)*132 + (bid >> 3);
  const int sp  = wg & 3;                  // col split (256 cols each)
  const int row0 = (wg >> 2) * 256;        // 264 row tiles

  const unsigned lds0 = (unsigned)(size_t)((__attribute__((address_space(3))) char*)smem);

  // ds_read bases: swizzle XOR term depends only on bits7-8 of lin = (col>>1)&3,
  // invariant in fragment index m/n -> frag offsets are plain +m*1024 immediates.
  unsigned aB[4], bB[4];
  {
    unsigned linA = (unsigned)((wr*128 + col)*64 + quad*16);
    unsigned swzA = linA ^ (((linA >> 7) & 3u) << 4);
    unsigned linB = (unsigned)((wc*64 + col)*64 + quad*16);
    unsigned swzB = linB ^ (((linB >> 7) & 3u) << 4);
    #pragma unroll
    for (int qq = 0; qq < 4; qq++){
      aB[qq] = lds0 + qq*32768 + swzA;
      bB[qq] = lds0 + qq*32768 + 16384 + swzB;
    }
  }

  // staging: 4 x global_load_lds(16B) per K-tile; linear LDS dest (uniform base,
  // HW adds lane*16), inverse-swizzled per-lane global source offset.
  const u16* gA = xb + (size_t)row0*ADIM;
  const u16* gB = wb + (size_t)(sp*256)*ADIM;
  unsigned off_[2];
  const int ldsd = wv*1024;
  #pragma unroll
  for (int jj = 0; jj < 2; jj++){
    unsigned d = (unsigned)(jj*8192 + wv*1024 + lane*16);
    unsigned sv = d ^ (((d >> 7) & 3u) << 4);
    off_[jj] = (sv >> 6)*ADIM + ((sv & 63u) >> 1);   // element offset
  }

#define STG4(TILE, NB) do{ \
  __builtin_amdgcn_global_load_lds((const __attribute__((address_space(1))) void*)(gA + off_[0] + (TILE)*32), \
      (__attribute__((address_space(3))) void*)(smem + (NB)*32768 + ldsd), 16, 0, 0); \
  __builtin_amdgcn_global_load_lds((const __attribute__((address_space(1))) void*)(gA + off_[1] + (TILE)*32), \
      (__attribute__((address_space(3))) void*)(smem + (NB)*32768 + 8192 + ldsd), 16, 0, 0); \
  __builtin_amdgcn_global_load_lds((const __attribute__((address_space(1))) void*)(gB + off_[0] + (TILE)*32), \
      (__attribute__((address_space(3))) void*)(smem + (NB)*32768 + 16384 + ldsd), 16, 0, 0); \
  __builtin_amdgcn_global_load_lds((const __attribute__((address_space(1))) void*)(gB + off_[1] + (TILE)*32), \
      (__attribute__((address_space(3))) void*)(smem + (NB)*32768 + 24576 + ldsd), 16, 0, 0); \
}while(0)

#define DSR(dst, base, off) asm volatile("ds_read_b128 %0, %1 offset:" #off : "=v"(dst) : "v"(base))
#define READT(QN, NA, NB) do{ \
  DSR(NA[0], aB[QN], 0);    DSR(NA[1], aB[QN], 1024); DSR(NA[2], aB[QN], 2048); DSR(NA[3], aB[QN], 3072); \
  DSR(NA[4], aB[QN], 4096); DSR(NA[5], aB[QN], 5120); DSR(NA[6], aB[QN], 6144); DSR(NA[7], aB[QN], 7168); \
  DSR(NB[0], bB[QN], 0);    DSR(NB[1], bB[QN], 1024); DSR(NB[2], bB[QN], 2048); DSR(NB[3], bB[QN], 3072); \
}while(0)

#define MFMAT(CA, CB) do{ \
  _Pragma("unroll") \
  for (int m_ = 0; m_ < 8; m_++){ \
    _Pragma("unroll") \
    for (int n_ = 0; n_ < 4; n_++) \
      acc[m_][n_] = __builtin_amdgcn_mfma_f32_16x16x32_bf16(CA[m_], CB[n_], acc[m_][n_], 0, 0, 0); \
  } \
}while(0)

#define BODY(TILE3, QN, QS, CA, CB, NA, NB) do{ \
  __builtin_amdgcn_s_barrier(); \
  __builtin_amdgcn_sched_barrier(0); \
  STG4((TILE3), QS); \
  asm volatile("s_waitcnt vmcnt(4)" ::: "memory"); \
  __builtin_amdgcn_sched_barrier(0); \
  READT(QN, NA, NB); \
  asm volatile("s_waitcnt lgkmcnt(12)" ::: "memory"); \
  __builtin_amdgcn_sched_barrier(0); \
  __builtin_amdgcn_s_setprio(1); \
  MFMAT(CA, CB); \
  __builtin_amdgcn_s_setprio(0); \
  __builtin_amdgcn_sched_barrier(0); \
}while(0)

  f32x4 acc[8][4];
  const f32x4 z = {0.f,0.f,0.f,0.f};
  #pragma unroll
  for (int m = 0; m < 8; m++)
    #pragma unroll
    for (int n = 0; n < 4; n++) acc[m][n] = z;

  bf16x8 pA[8], pB[4], oA[8], oB[4];

  // prologue: stage tiles 0,1,2; publish 0,1; read tile 0 into ping
  STG4(0, 0); STG4(1, 1); STG4(2, 2);
  asm volatile("s_waitcnt vmcnt(4)" ::: "memory");   // my tiles 0,1 landed
  __builtin_amdgcn_sched_barrier(0);
  __builtin_amdgcn_s_barrier();                      // all waves' tiles 0,1 landed
  __builtin_amdgcn_sched_barrier(0);
  READT(0, pA, pB);

  // main loop: kt = 0..27 (stages tiles 3..30), x4 unrolled for static ping-pong
  for (int b4 = 0; b4 < 7; b4++){
    const int kt = b4*4;
    BODY(kt+3, 1, 3, pA, pB, oA, oB);
    BODY(kt+4, 2, 0, oA, oB, pA, pB);
    BODY(kt+5, 3, 1, pA, pB, oA, oB);
    BODY(kt+6, 0, 2, oA, oB, pA, pB);
  }

  // kt=28: stage tile 31, read tile 29, compute 28
  BODY(31, 1, 3, pA, pB, oA, oB);
  // kt=29: read tile 30, compute 29
  __builtin_amdgcn_s_barrier();
  __builtin_amdgcn_sched_barrier(0);
  asm volatile("s_waitcnt vmcnt(0)" ::: "memory");
  __builtin_amdgcn_sched_barrier(0);
  READT(2, pA, pB);
  asm volatile("s_waitcnt lgkmcnt(12)" ::: "memory");
  __builtin_amdgcn_sched_barrier(0);
  __builtin_amdgcn_s_setprio(1);
  MFMAT(oA, oB);
  __builtin_amdgcn_s_setprio(0);
  // kt=30: read tile 31 (published by this barrier), compute 30
  __builtin_amdgcn_s_barrier();
  __builtin_amdgcn_sched_barrier(0);
  READT(3, oA, oB);
  asm volatile("s_waitcnt lgkmcnt(12)" ::: "memory");
  __builtin_amdgcn_sched_barrier(0);
  __builtin_amdgcn_s_setprio(1);
  MFMAT(pA, pB);
  __builtin_amdgcn_s_setprio(0);
  // kt=31
  asm volatile("s_waitcnt lgkmcnt(0)" ::: "memory");
  __builtin_amdgcn_sched_barrier(0);
  __builtin_amdgcn_s_setprio(1);
  MFMAT(oA, oB);
  __builtin_amdgcn_s_setprio(0);

#undef BODY
#undef MFMAT
#undef READT
#undef DSR
#undef STG4

  // ---- epilogue: per-row max/expsum/label over wave's 64 cols, then LDS-merge
  float bias[4];
  #pragma unroll
  for (int n = 0; n < 4; n++) bias[n] = biasv[sp*256 + wc*64 + n*16 + col];

  __syncthreads();                    // all waves done with LDS tiles
  float* red = (float*)smem;          // [3][256][4] = 12 KB

  #pragma unroll
  for (int m = 0; m < 8; m++){
    #pragma unroll
    for (int rg = 0; rg < 4; rg++){
      const int rb = wr*128 + m*16 + quad*4 + rg;
      const int gr = row0 + rb;
      int lbl = -1;
      if (gr < NROWS) lbl = tgt[gr];
      else if (gr < MROWS){ int a_ = gr - NROWS; lbl = (a_ < CCLS) ? a_ : a_ - CCLS; }
      float lg[4];
      float mx = NEG_INF, lv = NEG_INF;
      #pragma unroll
      for (int n = 0; n < 4; n++){
        float v = acc[m][n][rg] + bias[n];
        lg[n] = v;
        mx = fmaxf(mx, v);
        int c = sp*256 + wc*64 + n*16 + col;
        lv = (c == lbl) ? v : lv;
      }
      #pragma unroll
      for (int o = 1; o < 16; o <<= 1) mx = fmaxf(mx, __shfl_xor(mx, o));
      float se = 0.f;
      #pragma unroll
      for (int n = 0; n < 4; n++) se += __expf(lg[n] - mx);
      #pragma unroll
      for (int o = 1; o < 16; o <<= 1) se += __shfl_xor(se, o);
      #pragma unroll
      for (int o = 1; o < 16; o <<= 1) lv = fmaxf(lv, __shfl_xor(lv, o));
      if (col == 0){
        red[0*1024 + rb*4 + wc] = mx;
        red[1*1024 + rb*4 + wc] = se;
        red[2*1024 + rb*4 + wc] = lv;
      }
    }
  }
  __syncthreads();
  if (t < 256){
    float m0 = red[t*4+0], m1 = red[t*4+1], m2 = red[t*4+2], m3 = red[t*4+3];
    float mx = fmaxf(fmaxf(m0,m1), fmaxf(m2,m3));
    float l  = red[1024+t*4+0]*__expf(m0-mx) + red[1024+t*4+1]*__expf(m1-mx)
             + red[1024+t*4+2]*__expf(m2-mx) + red[1024+t*4+3]*__expf(m3-mx);
    float lv = fmaxf(fmaxf(red[2048+t*4+0],red[2048+t*4+1]),
                     fmaxf(red[2048+t*4+2],red[2048+t*4+3]));
    size_t idx = (size_t)sp*MPAD + (size_t)(row0 + t);
    pm[idx]   = mx;
    pl[idx]   = l;
    plab[idx] = lv;
  }
}

// ---------------- merge 4 partials -> loss (scaled, atomic into out) ----------------
__global__ void k_merge(const float* __restrict__ pm, const float* __restrict__ pl,
                        const float* __restrict__ plab, float* __restrict__ out){
  int r = blockIdx.x*256 + threadIdx.x;
  float v = 0.f;
  if (r < MROWS){
    float m = NEG_INF, lb = NEG_INF;
    #pragma unroll
    for (int s = 0; s < NPART; s++){
      m  = fmaxf(m,  pm[(size_t)s*MPAD + r]);
      lb = fmaxf(lb, plab[(size_t)s*MPAD + r]);
    }
    float l = 0.f;
    #pragma unroll
    for (int s = 0; s < NPART; s++)
      l += pl[(size_t)s*MPAD + r]*__expf(pm[(size_t)s*MPAD + r] - m);
    v = (m + __logf(l) - lb) * (1.0f/(float)MROWS);
  }
  #pragma unroll
  for (int o = 32; o > 0; o >>= 1) v += __shfl_xor(v, o);
  if ((threadIdx.x & 63) == 0) atomicAdd(out, v);
}

extern "C" void kernel_launch(void* const* d_in, const int* in_sizes, int n_in,
                              void* d_out, int out_size, void* d_ws, size_t ws_size,
                              hipStream_t stream) {
  const float* x     = (const float*)d_in[0];
  const float* eps   = (const float*)d_in[1];
  const float* fc_w  = (const float*)d_in[2];
  const float* fc_b  = (const float*)d_in[3];
  const float* ba    = (const float*)d_in[4];
  const float* cov_p = (const float*)d_in[5];
  const float* ave_p = (const float*)d_in[6];
  const float* amt_p = (const float*)d_in[7];
  const int*   tgt   = (const int*)d_in[8];
  float* out = (float*)d_out;

  char* ws = (char*)d_ws;
  u16*   xb    = (u16*)(ws);                         // 138,412,032 B
  u16*   wb    = (u16*)(ws + 138412032u);            // 2,097,152 B
  float* biasv = (float*)(ws + 140509184u);          // 4096 B
  int*   sorted= (int*)(ws + 140513280u);            // 262,144 B
  int*   cnt   = (int*)(ws + 140775424u);            // 4096
  int*   pos   = (int*)(ws + 140779520u);            // 4096
  int*   start = (int*)(ws + 140783616u);            // 4096
  float* pm    = (float*)(ws + 140787712u);          // 2,162,688
  float* pl    = (float*)(ws + 142950400u);          // 2,162,688
  float* plab  = (float*)(ws + 145113088u);          // 2,162,688

  static int cfg = 0;
  if (!cfg){
    hipFuncSetAttribute((const void*)k_gemm_part,
                        hipFuncAttributeMaxDynamicSharedMemorySize, 131072);
    cfg = 1;
  }

  hipMemsetAsync(cnt, 0, 12288, stream);             // cnt, pos, start
  hipMemsetAsync(out, 0, sizeof(float), stream);

  k_hist   <<<256, 256, 0, stream>>>(tgt, cnt);
  k_scan   <<<1, 1024, 0, stream>>>(cnt, start);
  k_scatter<<<256, 256, 0, stream>>>(tgt, start, pos, sorted);
  k_cvt_x  <<<32768, 256, 0, stream>>>(x, xb);
  k_pad    <<<24, 256, 0, stream>>>(xb);
  k_cvt_w  <<<512, 256, 0, stream>>>(fc_w, wb);
  k_bias   <<<4, 256, 0, stream>>>(fc_b, ba, biasv);
  k_stats  <<<CCLS, 256, 0, stream>>>(xb, sorted, cnt, start, amt_p, cov_p, ave_p, eps, xb);
  k_gemm_part<<<1056, 512, 131072, stream>>>(xb, wb, biasv, tgt, pm, pl, plab);
  k_merge  <<<264, 256, 0, stream>>>(pm, pl, plab, out);
}

// Round 3
// 677.871 us; speedup vs baseline: 1.0609x; 1.0609x over previous
//
#include <hip/hip_runtime.h>

#define NROWS 65536
#define ADIM  1024
#define CCLS  1000
#define SAUG  2
#define MROWS (NROWS + SAUG*CCLS)   /* 67536 */
#define MPAD  67584                 /* 264*256 */
#define NPAD  1024
#define NPART 4
#define NEG_INF (-3.0e38f)

typedef __bf16 bf16x8 __attribute__((ext_vector_type(8)));
typedef float  f32x4  __attribute__((ext_vector_type(4)));
typedef unsigned short u16;

#define AS1 __attribute__((address_space(1)))
#define AS3 __attribute__((address_space(3)))

__device__ __forceinline__ unsigned pk2bf(float a, float b){
  unsigned ua = __float_as_uint(a), ub = __float_as_uint(b);
  ua = (ua + 0x7FFFu + ((ua>>16)&1u)) >> 16;
  ub = (ub + 0x7FFFu + ((ub>>16)&1u)) >> 16;
  return ua | (ub<<16);
}
__device__ __forceinline__ float bflo(unsigned u){ return __uint_as_float((u & 0xFFFFu) << 16); }
__device__ __forceinline__ float bfhi(unsigned u){ return __uint_as_float(u & 0xFFFF0000u); }

// ---------------- histogram of labels ----------------
__global__ void k_hist(const int* __restrict__ tgt, int* __restrict__ cnt){
  int i = blockIdx.x*blockDim.x + threadIdx.x;
  int stride = gridDim.x*blockDim.x;
  for (; i < NROWS; i += stride) atomicAdd(&cnt[tgt[i]], 1);
}

// ---------------- exclusive scan over 1000 counts ----------------
__global__ void k_scan(const int* __restrict__ cnt, int* __restrict__ start){
  __shared__ int s[1024];
  int t = threadIdx.x;
  int v = (t < CCLS) ? cnt[t] : 0;
  s[t] = v;
  __syncthreads();
  for (int off = 1; off < 1024; off <<= 1){
    int u = (t >= off) ? s[t-off] : 0;
    __syncthreads();
    s[t] += u;
    __syncthreads();
  }
  if (t < CCLS) start[t] = s[t] - v;   // exclusive
}

// ---------------- scatter row indices grouped by class ----------------
__global__ void k_scatter(const int* __restrict__ tgt, const int* __restrict__ start,
                          int* __restrict__ pos, int* __restrict__ sorted){
  int i = blockIdx.x*blockDim.x + threadIdx.x;
  int stride = gridDim.x*blockDim.x;
  for (; i < NROWS; i += stride){
    int c = tgt[i];
    int r = atomicAdd(&pos[c], 1);
    sorted[start[c] + r] = i;
  }
}

// ---------------- x rows -> bf16 ----------------
__global__ void k_cvt_x(const float* __restrict__ x, u16* __restrict__ xb){
  size_t i = ((size_t)blockIdx.x*blockDim.x + threadIdx.x)*8;
  float4 a = *(const float4*)(x+i);
  float4 b = *(const float4*)(x+i+4);
  uint4 o;
  o.x = pk2bf(a.x,a.y); o.y = pk2bf(a.z,a.w);
  o.z = pk2bf(b.x,b.y); o.w = pk2bf(b.z,b.w);
  *(uint4*)(xb+i) = o;
}

// ---------------- zero pad tail rows of xb ----------------
__global__ void k_pad(u16* __restrict__ xb){
  size_t i = ((size_t)blockIdx.x*blockDim.x + threadIdx.x)*8 + (size_t)MROWS*ADIM;
  uint4 z = {0u,0u,0u,0u};
  *(uint4*)(xb+i) = z;
}

// ---------------- fc_w -> bf16 (pad classes to 1024 with zeros) ----------------
__global__ void k_cvt_w(const float* __restrict__ w, u16* __restrict__ wb){
  size_t i = ((size_t)blockIdx.x*blockDim.x + threadIdx.x)*8;
  int row = (int)(i >> 10);
  uint4 o = {0u,0u,0u,0u};
  if (row < CCLS){
    float4 a = *(const float4*)(w+i);
    float4 b = *(const float4*)(w+i+4);
    o.x = pk2bf(a.x,a.y); o.y = pk2bf(a.z,a.w);
    o.z = pk2bf(b.x,b.y); o.w = pk2bf(b.z,b.w);
  }
  *(uint4*)(wb+i) = o;
}

// ---------------- combined bias (NEG_INF masks pad classes) ----------------
__global__ void k_bias(const float* __restrict__ fc_b, const float* __restrict__ ba,
                       float* __restrict__ biasv){
  int c = blockIdx.x*blockDim.x + threadIdx.x;
  if (c < NPAD) biasv[c] = (c < CCLS) ? fc_b[c] - ba[c] : NEG_INF;
}

// ---------------- per-class stats + augmentation rows ----------------
__global__ void k_stats(const u16* __restrict__ xb_in, const int* __restrict__ sorted,
                        const int* __restrict__ cnt, const int* __restrict__ start,
                        const float* __restrict__ amt_p, const float* __restrict__ cov_p,
                        const float* __restrict__ ave_p, const float* __restrict__ eps,
                        u16* __restrict__ xb){
  __shared__ int sidx[256];
  int c = blockIdx.x;
  int t = threadIdx.x;
  int col = t*4;
  int n = cnt[c];
  int st = start[c];
  float s[4] = {0.f,0.f,0.f,0.f}, q[4] = {0.f,0.f,0.f,0.f};
  for (int base = 0; base < n; base += 256){
    int m = min(256, n - base);
    __syncthreads();
    if (t < m) sidx[t] = sorted[st + base + t];
    __syncthreads();
    int i = 0;
    for (; i + 4 <= m; i += 4){
      int r0 = sidx[i], r1 = sidx[i+1], r2 = sidx[i+2], r3 = sidx[i+3];
      uint2 u0 = *(const uint2*)(xb_in + (size_t)r0*ADIM + col);
      uint2 u1 = *(const uint2*)(xb_in + (size_t)r1*ADIM + col);
      uint2 u2 = *(const uint2*)(xb_in + (size_t)r2*ADIM + col);
      uint2 u3 = *(const uint2*)(xb_in + (size_t)r3*ADIM + col);
      {
        float v0=bflo(u0.x), v1=bfhi(u0.x), v2=bflo(u0.y), v3=bfhi(u0.y);
        s[0]+=v0; s[1]+=v1; s[2]+=v2; s[3]+=v3;
        q[0]+=v0*v0; q[1]+=v1*v1; q[2]+=v2*v2; q[3]+=v3*v3;
      }
      {
        float v0=bflo(u1.x), v1=bfhi(u1.x), v2=bflo(u1.y), v3=bfhi(u1.y);
        s[0]+=v0; s[1]+=v1; s[2]+=v2; s[3]+=v3;
        q[0]+=v0*v0; q[1]+=v1*v1; q[2]+=v2*v2; q[3]+=v3*v3;
      }
      {
        float v0=bflo(u2.x), v1=bfhi(u2.x), v2=bflo(u2.y), v3=bfhi(u2.y);
        s[0]+=v0; s[1]+=v1; s[2]+=v2; s[3]+=v3;
        q[0]+=v0*v0; q[1]+=v1*v1; q[2]+=v2*v2; q[3]+=v3*v3;
      }
      {
        float v0=bflo(u3.x), v1=bfhi(u3.x), v2=bflo(u3.y), v3=bfhi(u3.y);
        s[0]+=v0; s[1]+=v1; s[2]+=v2; s[3]+=v3;
        q[0]+=v0*v0; q[1]+=v1*v1; q[2]+=v2*v2; q[3]+=v3*v3;
      }
    }
    for (; i < m; i++){
      int row = sidx[i];
      const uint2 uv = *(const uint2*)(xb_in + (size_t)row*ADIM + col);
      float v0 = bflo(uv.x), v1 = bfhi(uv.x), v2 = bflo(uv.y), v3 = bfhi(uv.y);
      s[0]+=v0; s[1]+=v1; s[2]+=v2; s[3]+=v3;
      q[0]+=v0*v0; q[1]+=v1*v1; q[2]+=v2*v2; q[3]+=v3*v3;
    }
  }
  float cf = (float)n;
  float cc = (n == 0) ? 1.f : cf;
  float wgt = cf / (cf + amt_p[c] + 1e-10f);
  float4 cv = *(const float4*)(cov_p + (size_t)c*ADIM + col);
  float4 av = *(const float4*)(ave_p + (size_t)c*ADIM + col);
  float cvp[4] = {cv.x,cv.y,cv.z,cv.w};
  float avp[4] = {av.x,av.y,av.z,av.w};
  float ncov[4], nave[4];
  #pragma unroll
  for (int j = 0; j < 4; j++){
    float ave = s[j]/cc;
    float var = (q[j] - 2.f*ave*s[j] + cf*ave*ave)/cc;
    if (var <= 0.f) var = 1e-10f;
    float add = wgt*(1.f-wgt)*(avp[j]-ave)*(avp[j]-ave);
    ncov[j] = cvp[j]*(1.f-wgt) + var*wgt + add;
    nave[j] = avp[j]*(1.f-wgt) + ave*wgt;
  }
  #pragma unroll
  for (int s_ = 0; s_ < SAUG; s_++){
    size_t eoff = ((size_t)(s_*CCLS + c))*ADIM + col;
    size_t roff = ((size_t)(NROWS + s_*CCLS + c))*ADIM + col;
    const float4 e = *(const float4*)(eps + eoff);
    uint2 o;
    o.x = pk2bf(nave[0]+ncov[0]*e.x, nave[1]+ncov[1]*e.y);
    o.y = pk2bf(nave[2]+ncov[2]*e.z, nave[3]+ncov[3]*e.w);
    *(uint2*)(xb + roff) = o;
  }
}

// ---------------- MFMA GEMM + softmax partials (m201 8-phase template) --------
// BM=BN=256, BK=64 (16 K-tiles, 8 iters x 2), 8 waves (2Mx4N), wave tile 128x64.
// LDS 128KB: buf d (d=0,1) at d*65536; A plane [ks][256r][32k] (row 64B) at 0;
// B plane at +32768. st_16x32 swizzle: byte ^= ((r>>3)&1)<<5 on gload SOURCE and
// ds_read addr (same involution). Counted vmcnt(4) at phases 2 & 6 only.
__global__ __launch_bounds__(512,2) void k_gemm_part(
    const u16* __restrict__ xb, const u16* __restrict__ wb,
    const float* __restrict__ biasv, const int* __restrict__ tgt,
    float* __restrict__ pm, float* __restrict__ pl, float* __restrict__ plab){
  extern __shared__ char smem[];
  const int t = threadIdx.x;
  const int lane = t & 63;
  const int wv = t >> 6;       // 0..7
  const int wr = wv >> 2;      // M half (128 rows)
  const int wc = wv & 3;       // N quarter (64 cols)
  const int col = lane & 15;
  const int quad = lane >> 4;

  // bijective XCD-chunk swizzle: 1056 = 8*132; all 4 col-splits of a row tile
  // land in one XCD -> A panel fetched once per XCD.
  const int bid = blockIdx.x;
  const int wg  = (bid & 7)*132 + (bid >> 3);
  const int sp  = wg & 3;
  const int row0 = (wg >> 2) * 256;

  const unsigned lds0 = (unsigned)(size_t)((AS3 char*)smem);

  // ds_read per-lane bases (swizzled); frag offsets are immediates.
  const unsigned swzq = (unsigned)((quad*16) ^ (((lane>>3)&1)*32));
  const unsigned vA0 = lds0 + (unsigned)((wr*128 + col)*64) + swzq;
  const unsigned vB0 = lds0 + 32768u + (unsigned)((wc*64 + col)*64) + swzq;
  const unsigned vA1 = vA0 + 65536u;
  const unsigned vB1 = vB0 + 65536u;

  // stage source pointers (per-lane, inverse-swizzled) and uniform LDS dest base
  const int ldsd = wv*1024;
  const int csw = ((lane&3)*8) ^ (((lane>>5)&1)*16);      // element offset in k
  const int rT  = wv*16 + (lane>>2);                      // row within 128-half
  const u16* pA = xb + (size_t)(row0 + rT)*ADIM + csw;
  const u16* pB = wb + (size_t)(sp*256 + rT)*ADIM + csw;

#define STG(PTR, DOFF, KOFF) do{ \
  __builtin_amdgcn_global_load_lds((const AS1 void*)((PTR) + (KOFF)), \
      (AS3 void*)(smem + (DOFF) + ldsd), 16, 0, 0); \
  __builtin_amdgcn_global_load_lds((const AS1 void*)((PTR) + (KOFF) + 131072), \
      (AS3 void*)(smem + (DOFF) + 8192 + ldsd), 16, 0, 0); \
}while(0)

#define DSR(dst, base, OFF) asm volatile("ds_read_b128 %0, %1 offset:" #OFF : "=v"(dst) : "v"(base))
#define RDA_K0LO(V) do{ DSR(a0,V,0);     DSR(a1,V,1024);  DSR(a2,V,2048);  DSR(a3,V,3072);  }while(0)
#define RDA_K0HI(V) do{ DSR(a0,V,4096);  DSR(a1,V,5120);  DSR(a2,V,6144);  DSR(a3,V,7168);  }while(0)
#define RDA_K1LO(V) do{ DSR(a0,V,16384); DSR(a1,V,17408); DSR(a2,V,18432); DSR(a3,V,19456); }while(0)
#define RDA_K1HI(V) do{ DSR(a0,V,20480); DSR(a1,V,21504); DSR(a2,V,22528); DSR(a3,V,23552); }while(0)
#define RDB_K0(V)   do{ DSR(b0,V,0);     DSR(b1,V,1024);  DSR(b2,V,2048);  DSR(b3,V,3072);  }while(0)
#define RDB_K1(V)   do{ DSR(b0,V,16384); DSR(b1,V,17408); DSR(b2,V,18432); DSR(b3,V,19456); }while(0)

#define MM(A_,B_,C_) C_ = __builtin_amdgcn_mfma_f32_16x16x32_bf16(A_,B_,C_,0,0,0)
#define MF16(MS) do{ \
  MM(a0,b0,acc[MS+0][0]); MM(a0,b1,acc[MS+0][1]); MM(a0,b2,acc[MS+0][2]); MM(a0,b3,acc[MS+0][3]); \
  MM(a1,b0,acc[MS+1][0]); MM(a1,b1,acc[MS+1][1]); MM(a1,b2,acc[MS+1][2]); MM(a1,b3,acc[MS+1][3]); \
  MM(a2,b0,acc[MS+2][0]); MM(a2,b1,acc[MS+2][1]); MM(a2,b2,acc[MS+2][2]); MM(a2,b3,acc[MS+2][3]); \
  MM(a3,b0,acc[MS+3][0]); MM(a3,b1,acc[MS+3][1]); MM(a3,b2,acc[MS+3][2]); MM(a3,b3,acc[MS+3][3]); \
}while(0)

#define VMW4 asm volatile("s_waitcnt vmcnt(4)" ::: "memory")
#define VMW0 asm volatile("s_waitcnt vmcnt(0)" ::: "memory")
#define BARMF(MS) do{ \
  __builtin_amdgcn_sched_barrier(0); \
  __builtin_amdgcn_s_barrier(); \
  asm volatile("s_waitcnt lgkmcnt(0)" ::: "memory"); \
  __builtin_amdgcn_sched_barrier(0); \
  __builtin_amdgcn_s_setprio(1); \
  MF16(MS); \
  __builtin_amdgcn_s_setprio(0); \
  __builtin_amdgcn_sched_barrier(0); \
  __builtin_amdgcn_s_barrier(); \
}while(0)

  f32x4 acc[8][4];
  const f32x4 z = {0.f,0.f,0.f,0.f};
  #pragma unroll
  for (int m = 0; m < 8; m++)
    #pragma unroll
    for (int n = 0; n < 4; n++) acc[m][n] = z;

  bf16x8 a0,a1,a2,a3,b0,b1,b2,b3;

  // prologue: tile0 (buf0, both ks) + tile1 ks0 (buf1) = 12 loads/thread
  STG(pA, 0,      0);  STG(pB, 32768,  0);
  STG(pA, 16384,  32); STG(pB, 49152,  32);
  STG(pA, 65536,  64); STG(pB, 98304,  64);
  VMW0;
  __builtin_amdgcn_sched_barrier(0);
  __builtin_amdgcn_s_barrier();

  // steady state: iter it computes tiles 2it (buf0), 2it+1 (buf1).
  // stage map (region freed 1 phase earlier; landed-guarantee via vmcnt+barrier):
  //  P1: A buf1.ks1 <- tile 2it+1   P5: A buf0.ks1 <- tile 2it+2
  //  P2: B buf1.ks1 <- tile 2it+1   P6: B buf0.ks1 <- tile 2it+2
  //  P3: A buf0.ks0 <- tile 2it+2   P7: A buf1.ks0 <- tile 2it+3
  //  P4: B buf0.ks0 <- tile 2it+2   P8: B buf1.ks0 <- tile 2it+3
  for (int it = 0; it < 7; it++){
    const int kb = it*128;
    // P1
    RDA_K0LO(vA0); RDB_K0(vB0); STG(pA, 81920,  kb+96);  BARMF(0);
    // P2
    RDA_K0HI(vA0);              STG(pB, 114688, kb+96);  VMW4; BARMF(4);
    // P3
    RDA_K1LO(vA0); RDB_K1(vB0); STG(pA, 0,      kb+128); BARMF(0);
    // P4
    RDA_K1HI(vA0);              STG(pB, 32768,  kb+128); BARMF(4);
    // P5
    RDA_K0LO(vA1); RDB_K0(vB1); STG(pA, 16384,  kb+160); BARMF(0);
    // P6
    RDA_K0HI(vA1);              STG(pB, 49152,  kb+160); VMW4; BARMF(4);
    // P7
    RDA_K1LO(vA1); RDB_K1(vB1); STG(pA, 65536,  kb+192); BARMF(0);
    // P8
    RDA_K1HI(vA1);              STG(pB, 98304,  kb+192); BARMF(4);
  }
  // final iter (tiles 14,15): only P1/P2 stage (tile15 ks1); drain with vmcnt(0) at P6
  {
    RDA_K0LO(vA0); RDB_K0(vB0); STG(pA, 81920,  992);    BARMF(0);
    RDA_K0HI(vA0);              STG(pB, 114688, 992);    VMW4; BARMF(4);
    RDA_K1LO(vA0); RDB_K1(vB0);                          BARMF(0);
    RDA_K1HI(vA0);                                       BARMF(4);
    RDA_K0LO(vA1); RDB_K0(vB1);                          BARMF(0);
    RDA_K0HI(vA1);                                       VMW0; BARMF(4);
    RDA_K1LO(vA1); RDB_K1(vB1);                          BARMF(0);
    RDA_K1HI(vA1);                                       BARMF(4);
  }

#undef BARMF
#undef VMW0
#undef VMW4
#undef MF16
#undef MM
#undef RDB_K1
#undef RDB_K0
#undef RDA_K1HI
#undef RDA_K1LO
#undef RDA_K0HI
#undef RDA_K0LO
#undef DSR
#undef STG

  // ---- epilogue: per-row max/expsum/label over wave's 64 cols, then LDS-merge
  float bias[4];
  #pragma unroll
  for (int n = 0; n < 4; n++) bias[n] = biasv[sp*256 + wc*64 + n*16 + col];

  __syncthreads();                    // all waves done with LDS tiles
  float* red = (float*)smem;          // [3][256][4] = 12 KB

  #pragma unroll
  for (int m = 0; m < 8; m++){
    #pragma unroll
    for (int rg = 0; rg < 4; rg++){
      const int rb = wr*128 + m*16 + quad*4 + rg;
      const int gr = row0 + rb;
      int lbl = -1;
      if (gr < NROWS) lbl = tgt[gr];
      else if (gr < MROWS){ int a_ = gr - NROWS; lbl = (a_ < CCLS) ? a_ : a_ - CCLS; }
      float lg[4];
      float mx = NEG_INF, lv = NEG_INF;
      #pragma unroll
      for (int n = 0; n < 4; n++){
        float v = acc[m][n][rg] + bias[n];
        lg[n] = v;
        mx = fmaxf(mx, v);
        int c = sp*256 + wc*64 + n*16 + col;
        lv = (c == lbl) ? v : lv;
      }
      #pragma unroll
      for (int o = 1; o < 16; o <<= 1) mx = fmaxf(mx, __shfl_xor(mx, o));
      float se = 0.f;
      #pragma unroll
      for (int n = 0; n < 4; n++) se += __expf(lg[n] - mx);
      #pragma unroll
      for (int o = 1; o < 16; o <<= 1) se += __shfl_xor(se, o);
      #pragma unroll
      for (int o = 1; o < 16; o <<= 1) lv = fmaxf(lv, __shfl_xor(lv, o));
      if (col == 0){
        red[0*1024 + rb*4 + wc] = mx;
        red[1*1024 + rb*4 + wc] = se;
        red[2*1024 + rb*4 + wc] = lv;
      }
    }
  }
  __syncthreads();
  if (t < 256){
    float m0 = red[t*4+0], m1 = red[t*4+1], m2 = red[t*4+2], m3 = red[t*4+3];
    float mx = fmaxf(fmaxf(m0,m1), fmaxf(m2,m3));
    float l  = red[1024+t*4+0]*__expf(m0-mx) + red[1024+t*4+1]*__expf(m1-mx)
             + red[1024+t*4+2]*__expf(m2-mx) + red[1024+t*4+3]*__expf(m3-mx);
    float lv = fmaxf(fmaxf(red[2048+t*4+0],red[2048+t*4+1]),
                     fmaxf(red[2048+t*4+2],red[2048+t*4+3]));
    size_t idx = (size_t)sp*MPAD + (size_t)(row0 + t);
    pm[idx]   = mx;
    pl[idx]   = l;
    plab[idx] = lv;
  }
}

// ---------------- merge 4 partials -> loss (scaled, atomic into out) ----------------
__global__ void k_merge(const float* __restrict__ pm, const float* __restrict__ pl,
                        const float* __restrict__ plab, float* __restrict__ out){
  int r = blockIdx.x*256 + threadIdx.x;
  float v = 0.f;
  if (r < MROWS){
    float m = NEG_INF, lb = NEG_INF;
    #pragma unroll
    for (int s = 0; s < NPART; s++){
      m  = fmaxf(m,  pm[(size_t)s*MPAD + r]);
      lb = fmaxf(lb, plab[(size_t)s*MPAD + r]);
    }
    float l = 0.f;
    #pragma unroll
    for (int s = 0; s < NPART; s++)
      l += pl[(size_t)s*MPAD + r]*__expf(pm[(size_t)s*MPAD + r] - m);
    v = (m + __logf(l) - lb) * (1.0f/(float)MROWS);
  }
  #pragma unroll
  for (int o = 32; o > 0; o >>= 1) v += __shfl_xor(v, o);
  if ((threadIdx.x & 63) == 0) atomicAdd(out, v);
}

extern "C" void kernel_launch(void* const* d_in, const int* in_sizes, int n_in,
                              void* d_out, int out_size, void* d_ws, size_t ws_size,
                              hipStream_t stream) {
  const float* x     = (const float*)d_in[0];
  const float* eps   = (const float*)d_in[1];
  const float* fc_w  = (const float*)d_in[2];
  const float* fc_b  = (const float*)d_in[3];
  const float* ba    = (const float*)d_in[4];
  const float* cov_p = (const float*)d_in[5];
  const float* ave_p = (const float*)d_in[6];
  const float* amt_p = (const float*)d_in[7];
  const int*   tgt   = (const int*)d_in[8];
  float* out = (float*)d_out;

  char* ws = (char*)d_ws;
  u16*   xb    = (u16*)(ws);                         // 138,412,032 B
  u16*   wb    = (u16*)(ws + 138412032u);            // 2,097,152 B
  float* biasv = (float*)(ws + 140509184u);          // 4096 B
  int*   sorted= (int*)(ws + 140513280u);            // 262,144 B
  int*   cnt   = (int*)(ws + 140775424u);            // 4096
  int*   pos   = (int*)(ws + 140779520u);            // 4096
  int*   start = (int*)(ws + 140783616u);            // 4096
  float* pm    = (float*)(ws + 140787712u);          // 2,162,688
  float* pl    = (float*)(ws + 142950400u);          // 2,162,688
  float* plab  = (float*)(ws + 145113088u);          // 2,162,688

  static int cfg = 0;
  if (!cfg){
    hipFuncSetAttribute((const void*)k_gemm_part,
                        hipFuncAttributeMaxDynamicSharedMemorySize, 131072);
    cfg = 1;
  }

  hipMemsetAsync(cnt, 0, 12288, stream);             // cnt, pos, start
  hipMemsetAsync(out, 0, sizeof(float), stream);

  k_hist   <<<256, 256, 0, stream>>>(tgt, cnt);
  k_scan   <<<1, 1024, 0, stream>>>(cnt, start);
  k_scatter<<<256, 256, 0, stream>>>(tgt, start, pos, sorted);
  k_cvt_x  <<<32768, 256, 0, stream>>>(x, xb);
  k_pad    <<<24, 256, 0, stream>>>(xb);
  k_cvt_w  <<<512, 256, 0, stream>>>(fc_w, wb);
  k_bias   <<<4, 256, 0, stream>>>(fc_b, ba, biasv);
  k_stats  <<<CCLS, 256, 0, stream>>>(xb, sorted, cnt, start, amt_p, cov_p, ave_p, eps, xb);
  k_gemm_part<<<1056, 512, 131072, stream>>>(xb, wb, biasv, tgt, pm, pl, plab);
  k_merge  <<<264, 256, 0, stream>>>(pm, pl, plab, out);
}

// Round 4
// 659.255 us; speedup vs baseline: 1.0909x; 1.0282x over previous
//
#include <hip/hip_runtime.h>

#define NROWS 65536
#define ADIM  1024
#define CCLS  1000
#define SAUG  2
#define MROWS (NROWS + SAUG*CCLS)   /* 67536 */
#define MPAD  67584                 /* 264*256 */
#define NPAD  1024
#define NPART 4
#define NEG_INF (-3.0e38f)

typedef __bf16 bf16x8 __attribute__((ext_vector_type(8)));
typedef float  f32x4  __attribute__((ext_vector_type(4)));
typedef unsigned short u16;

#define AS1 __attribute__((address_space(1)))
#define AS3 __attribute__((address_space(3)))

__device__ __forceinline__ unsigned pk2bf(float a, float b){
  unsigned ua = __float_as_uint(a), ub = __float_as_uint(b);
  ua = (ua + 0x7FFFu + ((ua>>16)&1u)) >> 16;
  ub = (ub + 0x7FFFu + ((ub>>16)&1u)) >> 16;
  return ua | (ub<<16);
}
__device__ __forceinline__ float bflo(unsigned u){ return __uint_as_float((u & 0xFFFFu) << 16); }
__device__ __forceinline__ float bfhi(unsigned u){ return __uint_as_float(u & 0xFFFF0000u); }

// ---------------- histogram of labels ----------------
__global__ void k_hist(const int* __restrict__ tgt, int* __restrict__ cnt){
  int i = blockIdx.x*blockDim.x + threadIdx.x;
  int stride = gridDim.x*blockDim.x;
  for (; i < NROWS; i += stride) atomicAdd(&cnt[tgt[i]], 1);
}

// ---------------- exclusive scan over 1000 counts ----------------
__global__ void k_scan(const int* __restrict__ cnt, int* __restrict__ start){
  __shared__ int s[1024];
  int t = threadIdx.x;
  int v = (t < CCLS) ? cnt[t] : 0;
  s[t] = v;
  __syncthreads();
  for (int off = 1; off < 1024; off <<= 1){
    int u = (t >= off) ? s[t-off] : 0;
    __syncthreads();
    s[t] += u;
    __syncthreads();
  }
  if (t < CCLS) start[t] = s[t] - v;   // exclusive
}

// ---------------- scatter row indices grouped by class ----------------
__global__ void k_scatter(const int* __restrict__ tgt, const int* __restrict__ start,
                          int* __restrict__ pos, int* __restrict__ sorted){
  int i = blockIdx.x*blockDim.x + threadIdx.x;
  int stride = gridDim.x*blockDim.x;
  for (; i < NROWS; i += stride){
    int c = tgt[i];
    int r = atomicAdd(&pos[c], 1);
    sorted[start[c] + r] = i;
  }
}

// ---------------- x rows -> bf16 ----------------
__global__ void k_cvt_x(const float* __restrict__ x, u16* __restrict__ xb){
  size_t i = ((size_t)blockIdx.x*blockDim.x + threadIdx.x)*8;
  float4 a = *(const float4*)(x+i);
  float4 b = *(const float4*)(x+i+4);
  uint4 o;
  o.x = pk2bf(a.x,a.y); o.y = pk2bf(a.z,a.w);
  o.z = pk2bf(b.x,b.y); o.w = pk2bf(b.z,b.w);
  *(uint4*)(xb+i) = o;
}

// ---------------- zero pad tail rows of xb ----------------
__global__ void k_pad(u16* __restrict__ xb){
  size_t i = ((size_t)blockIdx.x*blockDim.x + threadIdx.x)*8 + (size_t)MROWS*ADIM;
  uint4 z = {0u,0u,0u,0u};
  *(uint4*)(xb+i) = z;
}

// ---------------- fc_w -> bf16 (pad classes to 1024 with zeros) ----------------
__global__ void k_cvt_w(const float* __restrict__ w, u16* __restrict__ wb){
  size_t i = ((size_t)blockIdx.x*blockDim.x + threadIdx.x)*8;
  int row = (int)(i >> 10);
  uint4 o = {0u,0u,0u,0u};
  if (row < CCLS){
    float4 a = *(const float4*)(w+i);
    float4 b = *(const float4*)(w+i+4);
    o.x = pk2bf(a.x,a.y); o.y = pk2bf(a.z,a.w);
    o.z = pk2bf(b.x,b.y); o.w = pk2bf(b.z,b.w);
  }
  *(uint4*)(wb+i) = o;
}

// ---------------- combined bias (NEG_INF masks pad classes) ----------------
__global__ void k_bias(const float* __restrict__ fc_b, const float* __restrict__ ba,
                       float* __restrict__ biasv){
  int c = blockIdx.x*blockDim.x + threadIdx.x;
  if (c < NPAD) biasv[c] = (c < CCLS) ? fc_b[c] - ba[c] : NEG_INF;
}

// ---------------- per-class stats + augmentation rows ----------------
__global__ void k_stats(const u16* __restrict__ xb_in, const int* __restrict__ sorted,
                        const int* __restrict__ cnt, const int* __restrict__ start,
                        const float* __restrict__ amt_p, const float* __restrict__ cov_p,
                        const float* __restrict__ ave_p, const float* __restrict__ eps,
                        u16* __restrict__ xb){
  __shared__ int sidx[256];
  int c = blockIdx.x;
  int t = threadIdx.x;
  int col = t*4;
  int n = cnt[c];
  int st = start[c];
  float s[4] = {0.f,0.f,0.f,0.f}, q[4] = {0.f,0.f,0.f,0.f};
  for (int base = 0; base < n; base += 256){
    int m = min(256, n - base);
    __syncthreads();
    if (t < m) sidx[t] = sorted[st + base + t];
    __syncthreads();
    int i = 0;
    for (; i + 4 <= m; i += 4){
      int r0 = sidx[i], r1 = sidx[i+1], r2 = sidx[i+2], r3 = sidx[i+3];
      uint2 u0 = *(const uint2*)(xb_in + (size_t)r0*ADIM + col);
      uint2 u1 = *(const uint2*)(xb_in + (size_t)r1*ADIM + col);
      uint2 u2 = *(const uint2*)(xb_in + (size_t)r2*ADIM + col);
      uint2 u3 = *(const uint2*)(xb_in + (size_t)r3*ADIM + col);
      {
        float v0=bflo(u0.x), v1=bfhi(u0.x), v2=bflo(u0.y), v3=bfhi(u0.y);
        s[0]+=v0; s[1]+=v1; s[2]+=v2; s[3]+=v3;
        q[0]+=v0*v0; q[1]+=v1*v1; q[2]+=v2*v2; q[3]+=v3*v3;
      }
      {
        float v0=bflo(u1.x), v1=bfhi(u1.x), v2=bflo(u1.y), v3=bfhi(u1.y);
        s[0]+=v0; s[1]+=v1; s[2]+=v2; s[3]+=v3;
        q[0]+=v0*v0; q[1]+=v1*v1; q[2]+=v2*v2; q[3]+=v3*v3;
      }
      {
        float v0=bflo(u2.x), v1=bfhi(u2.x), v2=bflo(u2.y), v3=bfhi(u2.y);
        s[0]+=v0; s[1]+=v1; s[2]+=v2; s[3]+=v3;
        q[0]+=v0*v0; q[1]+=v1*v1; q[2]+=v2*v2; q[3]+=v3*v3;
      }
      {
        float v0=bflo(u3.x), v1=bfhi(u3.x), v2=bflo(u3.y), v3=bfhi(u3.y);
        s[0]+=v0; s[1]+=v1; s[2]+=v2; s[3]+=v3;
        q[0]+=v0*v0; q[1]+=v1*v1; q[2]+=v2*v2; q[3]+=v3*v3;
      }
    }
    for (; i < m; i++){
      int row = sidx[i];
      const uint2 uv = *(const uint2*)(xb_in + (size_t)row*ADIM + col);
      float v0 = bflo(uv.x), v1 = bfhi(uv.x), v2 = bflo(uv.y), v3 = bfhi(uv.y);
      s[0]+=v0; s[1]+=v1; s[2]+=v2; s[3]+=v3;
      q[0]+=v0*v0; q[1]+=v1*v1; q[2]+=v2*v2; q[3]+=v3*v3;
    }
  }
  float cf = (float)n;
  float cc = (n == 0) ? 1.f : cf;
  float wgt = cf / (cf + amt_p[c] + 1e-10f);
  float4 cv = *(const float4*)(cov_p + (size_t)c*ADIM + col);
  float4 av = *(const float4*)(ave_p + (size_t)c*ADIM + col);
  float cvp[4] = {cv.x,cv.y,cv.z,cv.w};
  float avp[4] = {av.x,av.y,av.z,av.w};
  float ncov[4], nave[4];
  #pragma unroll
  for (int j = 0; j < 4; j++){
    float ave = s[j]/cc;
    float var = (q[j] - 2.f*ave*s[j] + cf*ave*ave)/cc;
    if (var <= 0.f) var = 1e-10f;
    float add = wgt*(1.f-wgt)*(avp[j]-ave)*(avp[j]-ave);
    ncov[j] = cvp[j]*(1.f-wgt) + var*wgt + add;
    nave[j] = avp[j]*(1.f-wgt) + ave*wgt;
  }
  #pragma unroll
  for (int s_ = 0; s_ < SAUG; s_++){
    size_t eoff = ((size_t)(s_*CCLS + c))*ADIM + col;
    size_t roff = ((size_t)(NROWS + s_*CCLS + c))*ADIM + col;
    const float4 e = *(const float4*)(eps + eoff);
    uint2 o;
    o.x = pk2bf(nave[0]+ncov[0]*e.x, nave[1]+ncov[1]*e.y);
    o.y = pk2bf(nave[2]+ncov[2]*e.z, nave[3]+ncov[3]*e.w);
    *(uint2*)(xb + roff) = o;
  }
}

// ---------------- MFMA GEMM + softmax partials (pipelined-register 8-phase) ----
// BM=BN=256, BK=64 (16 K-tiles, 8 iters x 2), 8 waves (2Mx4N), wave tile 128x64.
// LDS 128KB: buf d at d*65536; A plane [2ks][256r][32k] at 0, B plane at +32768.
// Schedule: phase p issues ds_reads for phase p+1 into the idle frag set, then
// counted lgkmcnt(n) and 16 MFMA on the live set -> LDS drain overlaps MFMA.
// Only 2 barriers/iter (publish points ph2/ph6): lgkmcnt(0)+vmcnt(0)+s_barrier.
// Swizzle (unchanged from R3, verified conflict-free): byte ^= ((lane>>3)&1)<<5
// applied identically to gload SOURCE and ds_read addr.
__global__ __launch_bounds__(512,2) void k_gemm_part(
    const u16* __restrict__ xb, const u16* __restrict__ wb,
    const float* __restrict__ biasv, const int* __restrict__ tgt,
    float* __restrict__ pm, float* __restrict__ pl, float* __restrict__ plab){
  extern __shared__ char smem[];
  const int t = threadIdx.x;
  const int lane = t & 63;
  const int wv = t >> 6;       // 0..7
  const int wr = wv >> 2;      // M half (128 rows)
  const int wc = wv & 3;       // N quarter (64 cols)
  const int col = lane & 15;
  const int quad = lane >> 4;

  // bijective XCD-chunk swizzle: 1056 = 8*132
  const int bid = blockIdx.x;
  const int wg  = (bid & 7)*132 + (bid >> 3);
  const int sp  = wg & 3;
  const int row0 = (wg >> 2) * 256;

  const unsigned lds0 = (unsigned)(size_t)((AS3 char*)smem);

  const unsigned swzq = (unsigned)((quad*16) ^ (((lane>>3)&1)*32));
  const unsigned vA0 = lds0 + (unsigned)((wr*128 + col)*64) + swzq;
  const unsigned vB0 = lds0 + 32768u + (unsigned)((wc*64 + col)*64) + swzq;
  const unsigned vA1 = vA0 + 65536u;
  const unsigned vB1 = vB0 + 65536u;

  const int ldsd = wv*1024;
  const int csw = ((lane&3)*8) ^ (((lane>>5)&1)*16);      // element offset in k
  const int rT  = wv*16 + (lane>>2);                      // row within 128-half
  const u16* pA = xb + (size_t)(row0 + rT)*ADIM + csw;
  const u16* pB = wb + (size_t)(sp*256 + rT)*ADIM + csw;

#define STG(PTR, DOFF, KOFF) do{ \
  __builtin_amdgcn_global_load_lds((const AS1 void*)((PTR) + (KOFF)), \
      (AS3 void*)(smem + (DOFF) + ldsd), 16, 0, 0); \
  __builtin_amdgcn_global_load_lds((const AS1 void*)((PTR) + (KOFF) + 131072), \
      (AS3 void*)(smem + (DOFF) + 8192 + ldsd), 16, 0, 0); \
}while(0)

#define DSR(dst, base, OFF) asm volatile("ds_read_b128 %0, %1 offset:" #OFF : "=v"(dst) : "v"(base))
#define RD4(D, V, O0,O1,O2,O3) do{ DSR(D[0],V,O0); DSR(D[1],V,O1); DSR(D[2],V,O2); DSR(D[3],V,O3); }while(0)

#define LGKM(N) do{ \
  asm volatile("s_waitcnt lgkmcnt(" #N ")" ::: "memory"); \
  __builtin_amdgcn_sched_barrier(0); \
}while(0)

#define MM(A_,B_,C_) C_ = __builtin_amdgcn_mfma_f32_16x16x32_bf16(A_,B_,C_,0,0,0)
#define MFC(AS_,BS_,MS) do{ \
  __builtin_amdgcn_s_setprio(1); \
  MM(AS_[0],BS_[0],acc[(MS)+0][0]); MM(AS_[0],BS_[1],acc[(MS)+0][1]); MM(AS_[0],BS_[2],acc[(MS)+0][2]); MM(AS_[0],BS_[3],acc[(MS)+0][3]); \
  MM(AS_[1],BS_[0],acc[(MS)+1][0]); MM(AS_[1],BS_[1],acc[(MS)+1][1]); MM(AS_[1],BS_[2],acc[(MS)+1][2]); MM(AS_[1],BS_[3],acc[(MS)+1][3]); \
  MM(AS_[2],BS_[0],acc[(MS)+2][0]); MM(AS_[2],BS_[1],acc[(MS)+2][1]); MM(AS_[2],BS_[2],acc[(MS)+2][2]); MM(AS_[2],BS_[3],acc[(MS)+2][3]); \
  MM(AS_[3],BS_[0],acc[(MS)+3][0]); MM(AS_[3],BS_[1],acc[(MS)+3][1]); MM(AS_[3],BS_[2],acc[(MS)+3][2]); MM(AS_[3],BS_[3],acc[(MS)+3][3]); \
  __builtin_amdgcn_s_setprio(0); \
  __builtin_amdgcn_sched_barrier(0); \
}while(0)

#define PUBLISH do{ \
  asm volatile("s_waitcnt lgkmcnt(0)" ::: "memory"); \
  asm volatile("s_waitcnt vmcnt(0)" ::: "memory"); \
  __builtin_amdgcn_sched_barrier(0); \
  __builtin_amdgcn_s_barrier(); \
  __builtin_amdgcn_sched_barrier(0); \
}while(0)

  f32x4 acc[8][4];
  const f32x4 z = {0.f,0.f,0.f,0.f};
  #pragma unroll
  for (int m = 0; m < 8; m++)
    #pragma unroll
    for (int n = 0; n < 4; n++) acc[m][n] = z;

  bf16x8 A0[4], A1[4], B0[4], B1[4];

  // prologue: tile0 -> buf0 (A+B), tile1-A -> buf1; publish tile0; pre-read ks0
  STG(pA, 0, 0);      STG(pA, 16384, 32);
  STG(pB, 32768, 0);  STG(pB, 49152, 32);
  STG(pA, 65536, 64); STG(pA, 81920, 96);
  asm volatile("s_waitcnt vmcnt(4)" ::: "memory");
  __builtin_amdgcn_sched_barrier(0);
  __builtin_amdgcn_s_barrier();
  __builtin_amdgcn_sched_barrier(0);
  RD4(A0, vA0, 0,1024,2048,3072);
  RD4(B0, vB0, 0,1024,2048,3072);

  // steady iters 0..6: compute tiles 2it (buf0), 2it+1 (buf1);
  // stage B-buf1<-2it+1 (ph0), A-buf0<-2it+2 (ph3), B-buf0<-2it+2 (ph4),
  // A-buf1<-2it+3 (ph7); publish at ph2 (buf1) and ph6 (buf0).
  for (int it = 0; it < 7; it++){
    const int SA = it*128;
    // ph0: MFMA(A0,B0 | ks0,mh0)
    STG(pB, 98304, SA+64); STG(pB, 114688, SA+96);
    RD4(A1, vA0, 4096,5120,6144,7168);
    LGKM(4);  MFC(A0,B0,0);
    // ph1: MFMA(A1,B0 | ks0,mh1)
    RD4(A0, vA0, 16384,17408,18432,19456);
    RD4(B1, vB0, 16384,17408,18432,19456);
    LGKM(8);  MFC(A1,B0,4);
    // ph2: MFMA(A0,B1 | ks1,mh0); publish buf1
    RD4(A1, vA0, 20480,21504,22528,23552);
    LGKM(4);  MFC(A0,B1,0);
    PUBLISH;
    // ph3: MFMA(A1,B1 | ks1,mh1)
    STG(pA, 0, SA+128); STG(pA, 16384, SA+160);
    RD4(A0, vA1, 0,1024,2048,3072);
    RD4(B0, vB1, 0,1024,2048,3072);
    LGKM(8);  MFC(A1,B1,4);
    // ph4: MFMA(A0,B0 | ks2,mh0)
    STG(pB, 32768, SA+128); STG(pB, 49152, SA+160);
    RD4(A1, vA1, 4096,5120,6144,7168);
    LGKM(4);  MFC(A0,B0,0);
    // ph5: MFMA(A1,B0 | ks2,mh1)
    RD4(A0, vA1, 16384,17408,18432,19456);
    RD4(B1, vB1, 16384,17408,18432,19456);
    LGKM(8);  MFC(A1,B0,4);
    // ph6: MFMA(A0,B1 | ks3,mh0); publish buf0
    RD4(A1, vA1, 20480,21504,22528,23552);
    LGKM(4);  MFC(A0,B1,0);
    PUBLISH;
    // ph7: MFMA(A1,B1 | ks3,mh1)
    STG(pA, 65536, SA+192); STG(pA, 81920, SA+224);
    RD4(A0, vA0, 0,1024,2048,3072);
    RD4(B0, vB0, 0,1024,2048,3072);
    LGKM(8);  MFC(A1,B1,4);
  }
  // final iter (tiles 14,15): stage only B-buf1<-tile15 at ph0; no ph6 barrier
  {
    STG(pB, 98304, 960); STG(pB, 114688, 992);
    RD4(A1, vA0, 4096,5120,6144,7168);
    LGKM(4);  MFC(A0,B0,0);
    RD4(A0, vA0, 16384,17408,18432,19456);
    RD4(B1, vB0, 16384,17408,18432,19456);
    LGKM(8);  MFC(A1,B0,4);
    RD4(A1, vA0, 20480,21504,22528,23552);
    LGKM(4);  MFC(A0,B1,0);
    PUBLISH;
    RD4(A0, vA1, 0,1024,2048,3072);
    RD4(B0, vB1, 0,1024,2048,3072);
    LGKM(8);  MFC(A1,B1,4);
    RD4(A1, vA1, 4096,5120,6144,7168);
    LGKM(4);  MFC(A0,B0,0);
    RD4(A0, vA1, 16384,17408,18432,19456);
    RD4(B1, vB1, 16384,17408,18432,19456);
    LGKM(8);  MFC(A1,B0,4);
    RD4(A1, vA1, 20480,21504,22528,23552);
    LGKM(4);  MFC(A0,B1,0);
    LGKM(0);  MFC(A1,B1,4);
  }

#undef PUBLISH
#undef MFC
#undef MM
#undef LGKM
#undef RD4
#undef DSR
#undef STG

  // ---- epilogue: per-row max/expsum/label over wave's 64 cols, then LDS-merge
  float bias[4];
  #pragma unroll
  for (int n = 0; n < 4; n++) bias[n] = biasv[sp*256 + wc*64 + n*16 + col];

  __syncthreads();                    // all waves done with LDS tiles
  float* red = (float*)smem;          // [3][256][4] = 12 KB

  #pragma unroll
  for (int m = 0; m < 8; m++){
    #pragma unroll
    for (int rg = 0; rg < 4; rg++){
      const int rb = wr*128 + m*16 + quad*4 + rg;
      const int gr = row0 + rb;
      int lbl = -1;
      if (gr < NROWS) lbl = tgt[gr];
      else if (gr < MROWS){ int a_ = gr - NROWS; lbl = (a_ < CCLS) ? a_ : a_ - CCLS; }
      float lg[4];
      float mx = NEG_INF, lv = NEG_INF;
      #pragma unroll
      for (int n = 0; n < 4; n++){
        float v = acc[m][n][rg] + bias[n];
        lg[n] = v;
        mx = fmaxf(mx, v);
        int c = sp*256 + wc*64 + n*16 + col;
        lv = (c == lbl) ? v : lv;
      }
      #pragma unroll
      for (int o = 1; o < 16; o <<= 1) mx = fmaxf(mx, __shfl_xor(mx, o));
      float se = 0.f;
      #pragma unroll
      for (int n = 0; n < 4; n++) se += __expf(lg[n] - mx);
      #pragma unroll
      for (int o = 1; o < 16; o <<= 1) se += __shfl_xor(se, o);
      #pragma unroll
      for (int o = 1; o < 16; o <<= 1) lv = fmaxf(lv, __shfl_xor(lv, o));
      if (col == 0){
        red[0*1024 + rb*4 + wc] = mx;
        red[1*1024 + rb*4 + wc] = se;
        red[2*1024 + rb*4 + wc] = lv;
      }
    }
  }
  __syncthreads();
  if (t < 256){
    float m0 = red[t*4+0], m1 = red[t*4+1], m2 = red[t*4+2], m3 = red[t*4+3];
    float mx = fmaxf(fmaxf(m0,m1), fmaxf(m2,m3));
    float l  = red[1024+t*4+0]*__expf(m0-mx) + red[1024+t*4+1]*__expf(m1-mx)
             + red[1024+t*4+2]*__expf(m2-mx) + red[1024+t*4+3]*__expf(m3-mx);
    float lv = fmaxf(fmaxf(red[2048+t*4+0],red[2048+t*4+1]),
                     fmaxf(red[2048+t*4+2],red[2048+t*4+3]));
    size_t idx = (size_t)sp*MPAD + (size_t)(row0 + t);
    pm[idx]   = mx;
    pl[idx]   = l;
    plab[idx] = lv;
  }
}

// ---------------- merge 4 partials -> loss (scaled, atomic into out) ----------------
__global__ void k_merge(const float* __restrict__ pm, const float* __restrict__ pl,
                        const float* __restrict__ plab, float* __restrict__ out){
  int r = blockIdx.x*256 + threadIdx.x;
  float v = 0.f;
  if (r < MROWS){
    float m = NEG_INF, lb = NEG_INF;
    #pragma unroll
    for (int s = 0; s < NPART; s++){
      m  = fmaxf(m,  pm[(size_t)s*MPAD + r]);
      lb = fmaxf(lb, plab[(size_t)s*MPAD + r]);
    }
    float l = 0.f;
    #pragma unroll
    for (int s = 0; s < NPART; s++)
      l += pl[(size_t)s*MPAD + r]*__expf(pm[(size_t)s*MPAD + r] - m);
    v = (m + __logf(l) - lb) * (1.0f/(float)MROWS);
  }
  #pragma unroll
  for (int o = 32; o > 0; o >>= 1) v += __shfl_xor(v, o);
  if ((threadIdx.x & 63) == 0) atomicAdd(out, v);
}

extern "C" void kernel_launch(void* const* d_in, const int* in_sizes, int n_in,
                              void* d_out, int out_size, void* d_ws, size_t ws_size,
                              hipStream_t stream) {
  const float* x     = (const float*)d_in[0];
  const float* eps   = (const float*)d_in[1];
  const float* fc_w  = (const float*)d_in[2];
  const float* fc_b  = (const float*)d_in[3];
  const float* ba    = (const float*)d_in[4];
  const float* cov_p = (const float*)d_in[5];
  const float* ave_p = (const float*)d_in[6];
  const float* amt_p = (const float*)d_in[7];
  const int*   tgt   = (const int*)d_in[8];
  float* out = (float*)d_out;

  char* ws = (char*)d_ws;
  u16*   xb    = (u16*)(ws);                         // 138,412,032 B
  u16*   wb    = (u16*)(ws + 138412032u);            // 2,097,152 B
  float* biasv = (float*)(ws + 140509184u);          // 4096 B
  int*   sorted= (int*)(ws + 140513280u);            // 262,144 B
  int*   cnt   = (int*)(ws + 140775424u);            // 4096
  int*   pos   = (int*)(ws + 140779520u);            // 4096
  int*   start = (int*)(ws + 140783616u);            // 4096
  float* pm    = (float*)(ws + 140787712u);          // 2,162,688
  float* pl    = (float*)(ws + 142950400u);          // 2,162,688
  float* plab  = (float*)(ws + 145113088u);          // 2,162,688

  static int cfg = 0;
  if (!cfg){
    hipFuncSetAttribute((const void*)k_gemm_part,
                        hipFuncAttributeMaxDynamicSharedMemorySize, 131072);
    cfg = 1;
  }

  hipMemsetAsync(cnt, 0, 12288, stream);             // cnt, pos, start
  hipMemsetAsync(out, 0, sizeof(float), stream);

  k_hist   <<<256, 256, 0, stream>>>(tgt, cnt);
  k_scan   <<<1, 1024, 0, stream>>>(cnt, start);
  k_scatter<<<256, 256, 0, stream>>>(tgt, start, pos, sorted);
  k_cvt_x  <<<32768, 256, 0, stream>>>(x, xb);
  k_pad    <<<24, 256, 0, stream>>>(xb);
  k_cvt_w  <<<512, 256, 0, stream>>>(fc_w, wb);
  k_bias   <<<4, 256, 0, stream>>>(fc_b, ba, biasv);
  k_stats  <<<CCLS, 256, 0, stream>>>(xb, sorted, cnt, start, amt_p, cov_p, ave_p, eps, xb);
  k_gemm_part<<<1056, 512, 131072, stream>>>(xb, wb, biasv, tgt, pm, pl, plab);
  k_merge  <<<264, 256, 0, stream>>>(pm, pl, plab, out);
}